// Round 5
// baseline (95.999 us; speedup 1.0000x reference)
//
#include <hip/hip_runtime.h>

#define CIN   64
#define HW    128
#define COUT  128
#define TH    4
#define TW    32
#define PXR   34
#define NITER (TH + 2)
#define NTHR  512
#define HSTR  144           // bytes per histogram row (16B aligned)
#define AKSTR 136           // u16 per AK row -> 272 B (16B aligned)

typedef int v4i __attribute__((ext_vector_type(4)));

// ---------------------------------------------------------------------------
// Kernel 1: W_tab[o] = sum of quantized weights; Kt_g[o][v] i8 = K[v][o]-128
// where K[v][o] = #{w in o : qw*(128+v) > 32767}, v=0..127 (K<=255, ~7 sigma).
// ---------------------------------------------------------------------------
__global__ __launch_bounds__(128)
void build_tables(const float* __restrict__ weight, int* __restrict__ W_tab,
                  char* __restrict__ Kt_g) {
  __shared__ int qw_s[576];
  __shared__ int red_s[128];
  const int o = blockIdx.x;
  const int t = threadIdx.x;
  int partial = 0;
  for (int j = t; j < 576; j += 128) {
    float w = weight[o * 576 + j];
    int q = (int)rintf(w * 255.f);
    q = q < 0 ? 0 : (q > 255 ? 255 : q);
    qw_s[j] = q;
    partial += q;
  }
  red_s[t] = partial;
  __syncthreads();
  for (int s = 64; s > 0; s >>= 1) {
    if (t < s) red_s[t] += red_s[t + s];
    __syncthreads();
  }
  if (t == 0) W_tab[o] = red_s[0];
  const int i = 128 + t;                     // t==0 -> cnt=0 (qw*128<=32640)
  int cnt = 0;
  for (int j = 0; j < 576; ++j) cnt += (qw_s[j] * i) > 32767 ? 1 : 0;
  Kt_g[o * 128 + t] = (char)(cnt - 128);
}

// ---------------------------------------------------------------------------
// Kernel 2: prefetched quantize -> histogram (LDS atomics) -> i8 MFMA
// (K = 3 stacked rows x 128 bins) -> horizontal 3-sum + emit.
// grid = (4,32,8) = 1024 blocks, 512 thr (8 waves), 44.7 KB LDS -> 3 blk/CU.
// stage map: l=t&15 channel-quad, slot=t>>4 pixel.
// mfma map :每wave 3 tasks T=w*3+j -> (Mt=T>>3, nt=T&7); all 8 waves.
// emit map : we=t&31 out col, og=t>>5.
// ---------------------------------------------------------------------------
__global__ __launch_bounds__(NTHR, 6)
void pcilt_main(const float* __restrict__ x, const float* __restrict__ bias,
                const int* __restrict__ W_tab, const char* __restrict__ Kt_g,
                float* __restrict__ out) {
  __shared__ unsigned char Hm[4][48 * HSTR];   // 27648 B: u8 bins
  __shared__ unsigned char KtAK[16384];        // Kt (prologue) then AK (i16)
  __shared__ int SxSH[4][40];                  // packed (pc<<20)|ps per pixel

  const int t  = (int)threadIdx.x;
  const int b  = (int)blockIdx.z;
  const int h0 = (int)blockIdx.y * TH;
  const int w0 = (int)blockIdx.x * TW;

  for (int i = t; i < 4096; i += NTHR)
    ((unsigned int*)KtAK)[i] = ((const unsigned int*)Kt_g)[i];
  {
    const uint4 z4 = make_uint4(0, 0, 0, 0);
    for (int i = t; i < 4 * 48 * HSTR / 16; i += NTHR) ((uint4*)Hm)[i] = z4;
    if (t < 160) ((int*)SxSH)[t] = 0;
  }

  const int l    = t & 15;
  const int slot = t >> 4;
  const int w    = t >> 6;
  const int kq   = (t >> 4) & 3;               // k-chunk within wave
  const int we   = t & 31;
  const int og   = t >> 5;

  float wf[8], bi[8];
#pragma unroll
  for (int m = 0; m < 8; ++m) {
    wf[m] = (float)W_tab[og * 8 + m];
    bi[m] = bias[og * 8 + m];
  }

  __syncthreads();

  // hoist 3 B-fragment tasks per wave: B[k][o] = K'[k][o]
  v4i bfr0[2], bfr1[2], bfr2[2];
  const int T0 = w * 3, T1 = T0 + 1, T2 = T0 + 2;
  const int Mt0 = T0 >> 3, nt0 = T0 & 7;
  const int Mt1 = T1 >> 3, nt1 = T1 & 7;
  const int Mt2 = T2 >> 3, nt2 = T2 & 7;
#pragma unroll
  for (int k64 = 0; k64 < 2; ++k64) {
    bfr0[k64] = *(const v4i*)(KtAK + (nt0 * 16 + l) * 128 + k64 * 64 + kq * 16);
    bfr1[k64] = *(const v4i*)(KtAK + (nt1 * 16 + l) * 128 + k64 * 64 + kq * 16);
    bfr2[k64] = *(const v4i*)(KtAK + (nt2 * 16 + l) * 128 + k64 * 64 + kq * 16);
  }
  unsigned short* AK = (unsigned short*)KtAK;  // reuse (first write at r=2,
                                               // all Kt reads fenced by r=0/1 barriers)

  // ---- prefetch state: pass0 = pixel slot, pass1 = pixel 32+slot (slot<2) --
  float pf0[4], pf1[4];
  const float* xb = x + ((size_t)b * CIN + l * 4) * (HW * HW);
  const size_t cs = (size_t)HW * HW;

#define ISSUE(rn)                                                              \
  {                                                                            \
    const int iy  = h0 + (rn)-1;                                              \
    const int iyc = iy < 0 ? 0 : (iy > 127 ? 127 : iy);                       \
    const bool rok = (iy >= 0) && (iy < HW);                                  \
    int ix = w0 + slot - 1;                                                   \
    int ixc = ix < 0 ? 0 : (ix > 127 ? 127 : ix);                             \
    bool ok = rok && (ix >= 0) && (ix < HW);                                  \
    const float* xp = xb + (size_t)iyc * HW + ixc;                            \
    float v0 = xp[0], v1 = xp[cs], v2 = xp[2 * cs], v3 = xp[3 * cs];          \
    pf0[0] = ok ? v0 : 0.f; pf0[1] = ok ? v1 : 0.f;                           \
    pf0[2] = ok ? v2 : 0.f; pf0[3] = ok ? v3 : 0.f;                           \
    if (slot < 2) {                                                           \
      ix = w0 + 32 + slot - 1;                                                \
      ixc = ix > 127 ? 127 : ix;                                              \
      ok = rok && (ix < HW);                                                  \
      const float* xq = xb + (size_t)iyc * HW + ixc;                          \
      float u0 = xq[0], u1 = xq[cs], u2 = xq[2 * cs], u3 = xq[3 * cs];        \
      pf1[0] = ok ? u0 : 0.f; pf1[1] = ok ? u1 : 0.f;                         \
      pf1[2] = ok ? u2 : 0.f; pf1[3] = ok ? u3 : 0.f;                         \
    }                                                                          \
  }

#define STAGEPX(pf, px, Hc, Sp)                                                \
  {                                                                            \
    int iv[4], ps = 0, pc = 0;                                                \
    _Pragma("unroll") for (int j = 0; j < 4; ++j) {                           \
      int q = (int)rintf((pf)[j] * 255.f);                                    \
      q = q < 0 ? 0 : (q > 255 ? 255 : q);                                    \
      iv[j] = q; ps += q; pc += (q > 128);                                    \
    }                                                                          \
    atomicAdd(&(Sp)[px], (pc << 20) + ps);                                    \
    unsigned char* hp = (Hc) + (px)*HSTR;                                     \
    _Pragma("unroll") for (int j = 0; j < 4; ++j) {                           \
      if (iv[j] > 128) {                                                      \
        int v = iv[j] - 128;                                                  \
        atomicAdd((unsigned int*)(hp + ((v >> 2) << 2)), 1u << ((v & 3) * 8));\
      }                                                                        \
    }                                                                          \
  }

  ISSUE(0);

  for (int r = 0; r < NITER; ++r) {
    // ---------------- stage-compute from prefetched regs -------------------
    {
      unsigned char* Hc = (unsigned char*)Hm[r & 3];
      int* Sp = SxSH[r & 3];
      STAGEPX(pf0, slot, Hc, Sp);
      if (slot < 2) STAGEPX(pf1, 32 + slot, Hc, Sp);
    }
    if (r + 1 < NITER) ISSUE(r + 1);
    __syncthreads();

    // ---------------- phase 2: MFMA (all waves, 3 tasks each) + zero -------
    if (r >= 2) {
      v4i acc0 = (v4i){0, 0, 0, 0}, acc1 = (v4i){0, 0, 0, 0}, acc2 = (v4i){0, 0, 0, 0};
#pragma unroll
      for (int st = 0; st < 3; ++st) {
        const unsigned char* Hb = (const unsigned char*)Hm[(r - 2 + st) & 3] +
                                  (t & 15) * HSTR + kq * 16;
#pragma unroll
        for (int k64 = 0; k64 < 2; ++k64) {
          const v4i aA = *(const v4i*)(Hb + Mt0 * (16 * HSTR) + k64 * 64);
          acc0 = __builtin_amdgcn_mfma_i32_16x16x64_i8(aA, bfr0[k64], acc0, 0, 0, 0);
          const v4i aB = *(const v4i*)(Hb + Mt1 * (16 * HSTR) + k64 * 64);
          acc1 = __builtin_amdgcn_mfma_i32_16x16x64_i8(aB, bfr1[k64], acc1, 0, 0, 0);
          const v4i aC = *(const v4i*)(Hb + Mt2 * (16 * HSTR) + k64 * 64);
          acc2 = __builtin_amdgcn_mfma_i32_16x16x64_i8(aC, bfr2[k64], acc2, 0, 0, 0);
        }
      }
      const int pb = kq * 4;
      const int oc = (t & 15);
#pragma unroll
      for (int rg = 0; rg < 4; ++rg) {
        AK[(Mt0 * 16 + pb + rg) * AKSTR + nt0 * 16 + oc] = (unsigned short)acc0[rg];
        AK[(Mt1 * 16 + pb + rg) * AKSTR + nt1 * 16 + oc] = (unsigned short)acc1[rg];
        AK[(Mt2 * 16 + pb + rg) * AKSTR + nt2 * 16 + oc] = (unsigned short)acc2[rg];
      }
    }
    if (r + 1 < NITER) {                       // zero next-row buffers
      const uint4 z4 = make_uint4(0, 0, 0, 0);
      uint4* Hn = (uint4*)Hm[(r + 1) & 3];
      for (int i = t; i < 34 * HSTR / 16; i += NTHR) Hn[i] = z4;
      if (t < 34) SxSH[(r + 1) & 3][t] = 0;
    }
    __syncthreads();

    // ---------------- emit out row h = h0 + r - 2 ---------------------------
    if (r >= 2) {
      const int h = h0 + r - 2;
      int v9 = 0;
#pragma unroll
      for (int q = 0; q < 3; ++q) {
        const int sl = (r - 2 + q) & 3;
        v9 += SxSH[sl][we] + SxSH[sl][we + 1] + SxSH[sl][we + 2];
      }
      const int sx9 = v9 & 0xFFFFF;
      const int sh9 = v9 >> 20;
      int k0 = 0, k1 = 0, k2 = 0, k3 = 0, k4 = 0, k5 = 0, k6 = 0, k7 = 0;
#pragma unroll
      for (int dx = 0; dx < 3; ++dx) {
        const uint4 p = *(const uint4*)&AK[(we + dx) * AKSTR + og * 8];
        k0 += (int)(short)(p.x & 0xffffu); k1 += (int)(short)(p.x >> 16);
        k2 += (int)(short)(p.y & 0xffffu); k3 += (int)(short)(p.y >> 16);
        k4 += (int)(short)(p.z & 0xffffu); k5 += (int)(short)(p.z >> 16);
        k6 += (int)(short)(p.w & 0xffffu); k7 += (int)(short)(p.w >> 16);
      }
      const int kc = 128 * sh9;
      const float sxf = (float)sx9;
      float* op = out + (((size_t)b * COUT + og * 8) * HW + h) * HW + (w0 + we);
      const size_t os = (size_t)HW * HW;
      op[0 * os] = sxf * wf[0] - 65536.f * (float)(k0 + kc) + bi[0];
      op[1 * os] = sxf * wf[1] - 65536.f * (float)(k1 + kc) + bi[1];
      op[2 * os] = sxf * wf[2] - 65536.f * (float)(k2 + kc) + bi[2];
      op[3 * os] = sxf * wf[3] - 65536.f * (float)(k3 + kc) + bi[3];
      op[4 * os] = sxf * wf[4] - 65536.f * (float)(k4 + kc) + bi[4];
      op[5 * os] = sxf * wf[5] - 65536.f * (float)(k5 + kc) + bi[5];
      op[6 * os] = sxf * wf[6] - 65536.f * (float)(k6 + kc) + bi[6];
      op[7 * os] = sxf * wf[7] - 65536.f * (float)(k7 + kc) + bi[7];
    }
  }
}

// ---------------------------------------------------------------------------
extern "C" void kernel_launch(void* const* d_in, const int* in_sizes, int n_in,
                              void* d_out, int out_size, void* d_ws, size_t ws_size,
                              hipStream_t stream) {
  const float* x      = (const float*)d_in[0];
  const float* weight = (const float*)d_in[1];
  const float* bias   = (const float*)d_in[2];
  float* out = (float*)d_out;

  int*  W_tab = (int*)d_ws;
  char* Kt_g  = (char*)d_ws + 512;

  build_tables<<<128, 128, 0, stream>>>(weight, W_tab, Kt_g);

  dim3 grid(HW / TW, HW / TH, 8);
  pcilt_main<<<grid, NTHR, 0, stream>>>(x, bias, W_tab, Kt_g, out);
}

// Round 6
// 47.377 us; speedup vs baseline: 2.0263x; 2.0263x over previous
//
#include <hip/hip_runtime.h>

#define CIN   64
#define HW    128
#define COUT  128
#define TH    8
#define TW    32
#define PXR   34
#define NITER (TH + 2)
#define NTHR  512
#define HSTR  144           // bytes per histogram row (16B aligned)
#define AKSTR 136           // u16 per AK row -> 272 B (16B aligned)

typedef int v4i __attribute__((ext_vector_type(4)));

// ---------------------------------------------------------------------------
// Kernel 1: W_tab[o] = sum of quantized weights; Kt_g[o][v] i8 = K[v][o]-128
// where K[v][o] = #{w in o : qw*(128+v) > 32767}, v=0..127 (K<=255, ~7 sigma).
// ---------------------------------------------------------------------------
__global__ __launch_bounds__(128)
void build_tables(const float* __restrict__ weight, int* __restrict__ W_tab,
                  char* __restrict__ Kt_g) {
  __shared__ int qw_s[576];
  __shared__ int red_s[128];
  const int o = blockIdx.x;
  const int t = threadIdx.x;
  int partial = 0;
  for (int j = t; j < 576; j += 128) {
    float w = weight[o * 576 + j];
    int q = (int)rintf(w * 255.f);
    q = q < 0 ? 0 : (q > 255 ? 255 : q);
    qw_s[j] = q;
    partial += q;
  }
  red_s[t] = partial;
  __syncthreads();
  for (int s = 64; s > 0; s >>= 1) {
    if (t < s) red_s[t] += red_s[t + s];
    __syncthreads();
  }
  if (t == 0) W_tab[o] = red_s[0];
  const int i = 128 + t;                     // t==0 -> cnt=0 (qw*128<=32640)
  int cnt = 0;
  for (int j = 0; j < 576; ++j) cnt += (qw_s[j] * i) > 32767 ? 1 : 0;
  Kt_g[o * 128 + t] = (char)(cnt - 128);
}

// ---------------------------------------------------------------------------
// Kernel 2: prefetched quantize -> histogram (LDS atomics) -> i8 MFMA
// (K = 3 stacked rows x 128 bins) -> horizontal 3-sum + emit.
// grid = 512 blocks (1D, XCD-remapped: b = bid&7 so each XCD owns one batch),
// block = 512 (8 waves), 58 KB LDS -> 2 blocks/CU.
// stage map: l=t&15 channel-quad, slot=t>>4 pixel.
// mfma map : waves 0..5 = (Mt=w>>1, Nh=w&1); waves 6,7 zero next H.
// emit map : we=t&31 out col, og=t>>5.
// ---------------------------------------------------------------------------
__global__ __launch_bounds__(NTHR, 4)
void pcilt_main(const float* __restrict__ x, const float* __restrict__ bias,
                const int* __restrict__ W_tab, const char* __restrict__ Kt_g,
                float* __restrict__ out) {
  __shared__ unsigned char Hm[4][48 * HSTR];       // 27648 B: u8 bins
  __shared__ unsigned char Kt[128 * 128];          // 16384 B: K'[o][v] i8
  __shared__ unsigned short AK[48 * AKSTR];        // 13056 B: HK' (i16)
  __shared__ int Sxr[4][PXR];
  __shared__ int SHr[4][PXR];

  const int t   = (int)threadIdx.x;
  const int bid = (int)blockIdx.x;
  // XCD remap: hardware round-robins consecutive bids over 8 XCDs -> bid&7 is
  // the XCD. Give each XCD one batch; within it, k>>2 = h-strip, k&3 = w-tile,
  // so the 4 blocks sharing output rows (and halo rows) are XCD-colocated.
  const int b  = bid & 7;
  const int k  = bid >> 3;                         // 0..63
  const int h0 = (k >> 2) * TH;
  const int w0 = (k & 3) * TW;

  for (int i = t; i < 128 * 128 / 4; i += NTHR)
    ((unsigned int*)Kt)[i] = ((const unsigned int*)Kt_g)[i];
  for (int i = t; i < 48 * HSTR / 4; i += NTHR)
    ((unsigned int*)Hm[0])[i] = 0u;

  const int l    = t & 15;
  const int slot = t >> 4;
  const int w    = t >> 6;
  const int kq   = (t >> 4) & 3;
  const int we   = t & 31;
  const int og   = t >> 5;

  float wf[8], bi[8];
#pragma unroll
  for (int m = 0; m < 8; ++m) {
    wf[m] = (float)W_tab[og * 8 + m];
    bi[m] = bias[og * 8 + m];
  }

  __syncthreads();

  // hoist B-fragments: B[k][o] = K'[k&127][o]
  v4i bfr[4][2];
  const int Mt = w >> 1, Nh = w & 1;
  if (w < 6) {
#pragma unroll
    for (int nt = 0; nt < 4; ++nt)
#pragma unroll
      for (int k64 = 0; k64 < 2; ++k64)
        bfr[nt][k64] = *(const v4i*)(Kt + (Nh * 64 + nt * 16 + l) * 128 +
                                     k64 * 64 + kq * 16);
  }

  // ---- prefetch state: pf0 = pixel slot, pf1 = pixel 32+slot (slot<2) -----
  float pf0[4], pf1[4];
  const float* xb = x + ((size_t)b * CIN + l * 4) * (HW * HW);
  const size_t cs = (size_t)HW * HW;

#define ISSUE(rn)                                                              \
  {                                                                            \
    const int iy  = h0 + (rn)-1;                                               \
    const int iyc = iy < 0 ? 0 : (iy > 127 ? 127 : iy);                        \
    const bool rok = (iy >= 0) && (iy < HW);                                   \
    int ix = w0 + slot - 1;                                                    \
    int ixc = ix < 0 ? 0 : (ix > 127 ? 127 : ix);                              \
    bool ok = rok && (ix >= 0) && (ix < HW);                                   \
    const float* xp = xb + (size_t)iyc * HW + ixc;                             \
    float v0 = xp[0], v1 = xp[cs], v2 = xp[2 * cs], v3 = xp[3 * cs];           \
    pf0[0] = ok ? v0 : 0.f; pf0[1] = ok ? v1 : 0.f;                            \
    pf0[2] = ok ? v2 : 0.f; pf0[3] = ok ? v3 : 0.f;                            \
    if (slot < 2) {                                                            \
      ix = w0 + 32 + slot - 1;                                                 \
      ixc = ix > 127 ? 127 : ix;                                               \
      ok = rok && (ix < HW);                                                   \
      const float* xq = xb + (size_t)iyc * HW + ixc;                           \
      float u0 = xq[0], u1 = xq[cs], u2 = xq[2 * cs], u3 = xq[3 * cs];         \
      pf1[0] = ok ? u0 : 0.f; pf1[1] = ok ? u1 : 0.f;                          \
      pf1[2] = ok ? u2 : 0.f; pf1[3] = ok ? u3 : 0.f;                          \
    }                                                                          \
  }

#define STAGEPX(pf, px)                                                        \
  {                                                                            \
    int q, iv0, iv1, iv2, iv3;                                                 \
    q = (int)rintf((pf)[0] * 255.f); iv0 = q < 0 ? 0 : (q > 255 ? 255 : q);    \
    q = (int)rintf((pf)[1] * 255.f); iv1 = q < 0 ? 0 : (q > 255 ? 255 : q);    \
    q = (int)rintf((pf)[2] * 255.f); iv2 = q < 0 ? 0 : (q > 255 ? 255 : q);    \
    q = (int)rintf((pf)[3] * 255.f); iv3 = q < 0 ? 0 : (q > 255 ? 255 : q);    \
    int ps = iv0 + iv1 + iv2 + iv3;                                            \
    int pc = (iv0 > 128) + (iv1 > 128) + (iv2 > 128) + (iv3 > 128);            \
    ps += __shfl_xor(ps, 1, 16); pc += __shfl_xor(pc, 1, 16);                  \
    ps += __shfl_xor(ps, 2, 16); pc += __shfl_xor(pc, 2, 16);                  \
    ps += __shfl_xor(ps, 4, 16); pc += __shfl_xor(pc, 4, 16);                  \
    ps += __shfl_xor(ps, 8, 16); pc += __shfl_xor(pc, 8, 16);                  \
    if (l == 0) { Sxr[r & 3][px] = ps; SHr[r & 3][px] = pc; }                  \
    unsigned char* hp = Hc + (px)*HSTR;                                        \
    if (iv0 > 128) { int v = iv0 - 128; atomicAdd((unsigned int*)(hp + ((v >> 2) << 2)), 1u << ((v & 3) * 8)); } \
    if (iv1 > 128) { int v = iv1 - 128; atomicAdd((unsigned int*)(hp + ((v >> 2) << 2)), 1u << ((v & 3) * 8)); } \
    if (iv2 > 128) { int v = iv2 - 128; atomicAdd((unsigned int*)(hp + ((v >> 2) << 2)), 1u << ((v & 3) * 8)); } \
    if (iv3 > 128) { int v = iv3 - 128; atomicAdd((unsigned int*)(hp + ((v >> 2) << 2)), 1u << ((v & 3) * 8)); } \
  }

  ISSUE(0);

  for (int r = 0; r < NITER; ++r) {
    // ---------------- stage from prefetched regs; issue next row -----------
    {
      unsigned char* Hc = (unsigned char*)Hm[r & 3];
      STAGEPX(pf0, slot);
      if (slot < 2) STAGEPX(pf1, 32 + slot);
    }
    if (r + 1 < NITER) ISSUE(r + 1);
    __syncthreads();

    // ---------------- phase 2: MFMA (waves 0-5) / zero next H (waves 6,7) --
    if (r >= 2 && w < 6) {
      v4i acc[4];
#pragma unroll
      for (int nt = 0; nt < 4; ++nt) acc[nt] = (v4i){0, 0, 0, 0};
      const int prow = Mt * 16 + (t & 15);
#pragma unroll
      for (int st = 0; st < 3; ++st) {
        const unsigned char* Hs = (const unsigned char*)Hm[(r - 2 + st) & 3] +
                                  prow * HSTR + kq * 16;
#pragma unroll
        for (int k64 = 0; k64 < 2; ++k64) {
          const v4i a = *(const v4i*)(Hs + k64 * 64);
#pragma unroll
          for (int nt = 0; nt < 4; ++nt)
            acc[nt] = __builtin_amdgcn_mfma_i32_16x16x64_i8(a, bfr[nt][k64], acc[nt], 0, 0, 0);
        }
      }
      const int pbase = Mt * 16 + kq * 4;
#pragma unroll
      for (int nt = 0; nt < 4; ++nt) {
        const int o = Nh * 64 + nt * 16 + (t & 15);
#pragma unroll
        for (int rg = 0; rg < 4; ++rg)
          AK[(pbase + rg) * AKSTR + o] = (unsigned short)acc[nt][rg];
      }
    }
    if (w >= 6) {
      uint4* Hn = (uint4*)Hm[(r + 1) & 3];
      const uint4 z4 = make_uint4(0, 0, 0, 0);
      for (int i = t - 384; i < 48 * HSTR / 16; i += 128) Hn[i] = z4;
    }
    __syncthreads();

    // ---------------- emit out row h = h0 + r - 2 ---------------------------
    if (r >= 2) {
      const int h = h0 + r - 2;
      int sx9 = 0, sh9 = 0;
#pragma unroll
      for (int q = 0; q < 3; ++q) {
        const int sl = (r - 2 + q) & 3;
        sx9 += Sxr[sl][we] + Sxr[sl][we + 1] + Sxr[sl][we + 2];
        sh9 += SHr[sl][we] + SHr[sl][we + 1] + SHr[sl][we + 2];
      }
      int k0 = 0, k1 = 0, k2 = 0, k3 = 0, k4 = 0, k5 = 0, k6 = 0, k7 = 0;
#pragma unroll
      for (int dx = 0; dx < 3; ++dx) {
        const uint4 p = *(const uint4*)&AK[(we + dx) * AKSTR + og * 8];
        k0 += (int)(short)(p.x & 0xffffu); k1 += (int)(short)(p.x >> 16);
        k2 += (int)(short)(p.y & 0xffffu); k3 += (int)(short)(p.y >> 16);
        k4 += (int)(short)(p.z & 0xffffu); k5 += (int)(short)(p.z >> 16);
        k6 += (int)(short)(p.w & 0xffffu); k7 += (int)(short)(p.w >> 16);
      }
      const int kc = 128 * sh9;
      const float sxf = (float)sx9;
      float* op = out + (((size_t)b * COUT + og * 8) * HW + h) * HW + (w0 + we);
      const size_t os = (size_t)HW * HW;
      op[0 * os] = sxf * wf[0] - 65536.f * (float)(k0 + kc) + bi[0];
      op[1 * os] = sxf * wf[1] - 65536.f * (float)(k1 + kc) + bi[1];
      op[2 * os] = sxf * wf[2] - 65536.f * (float)(k2 + kc) + bi[2];
      op[3 * os] = sxf * wf[3] - 65536.f * (float)(k3 + kc) + bi[3];
      op[4 * os] = sxf * wf[4] - 65536.f * (float)(k4 + kc) + bi[4];
      op[5 * os] = sxf * wf[5] - 65536.f * (float)(k5 + kc) + bi[5];
      op[6 * os] = sxf * wf[6] - 65536.f * (float)(k6 + kc) + bi[6];
      op[7 * os] = sxf * wf[7] - 65536.f * (float)(k7 + kc) + bi[7];
    }
  }
}

// ---------------------------------------------------------------------------
extern "C" void kernel_launch(void* const* d_in, const int* in_sizes, int n_in,
                              void* d_out, int out_size, void* d_ws, size_t ws_size,
                              hipStream_t stream) {
  const float* x      = (const float*)d_in[0];
  const float* weight = (const float*)d_in[1];
  const float* bias   = (const float*)d_in[2];
  float* out = (float*)d_out;

  int*  W_tab = (int*)d_ws;
  char* Kt_g  = (char*)d_ws + 512;

  build_tables<<<128, 128, 0, stream>>>(weight, W_tab, Kt_g);

  pcilt_main<<<512, NTHR, 0, stream>>>(x, bias, W_tab, Kt_g, out);
}

// Round 7
// 46.518 us; speedup vs baseline: 2.0637x; 1.0185x over previous
//
#include <hip/hip_runtime.h>

#define CIN   64
#define HW    128
#define COUT  128
#define TH    8
#define TW    32
#define PXR   34
#define NITER (TH + 3)      // 11 iterations, one barrier each
#define NTHR  512
#define HSTR  144           // bytes per histogram row (16B aligned)
#define AKSTR 136           // u16 per AK row -> 272 B (16B aligned)

typedef int v4i __attribute__((ext_vector_type(4)));

// lgkm-only barrier: drains LDS ops, leaves global loads/stores in flight
// (avoids the compiler's vmcnt(0) drain in __syncthreads; register deps on
// in-flight loads get compiler-inserted vmcnt at use).
__device__ __forceinline__ void wg_barrier() {
  asm volatile("s_waitcnt lgkmcnt(0)\n\ts_barrier" ::: "memory");
}

// ---------------------------------------------------------------------------
// Kernel 1: W_tab[o] = sum of quantized weights; Kt_g[o][v] i8 = K[v][o]-128
// where K[v][o] = #{w in o : qw*(128+v) > 32767}, v=0..127 (K<=255, ~7 sigma).
// ---------------------------------------------------------------------------
__global__ __launch_bounds__(128)
void build_tables(const float* __restrict__ weight, int* __restrict__ W_tab,
                  char* __restrict__ Kt_g) {
  __shared__ int qw_s[576];
  __shared__ int red_s[128];
  const int o = blockIdx.x;
  const int t = threadIdx.x;
  int partial = 0;
  for (int j = t; j < 576; j += 128) {
    float w = weight[o * 576 + j];
    int q = (int)rintf(w * 255.f);
    q = q < 0 ? 0 : (q > 255 ? 255 : q);
    qw_s[j] = q;
    partial += q;
  }
  red_s[t] = partial;
  __syncthreads();
  for (int s = 64; s > 0; s >>= 1) {
    if (t < s) red_s[t] += red_s[t + s];
    __syncthreads();
  }
  if (t == 0) W_tab[o] = red_s[0];
  const int i = 128 + t;                     // t==0 -> cnt=0 (qw*128<=32640)
  int cnt = 0;
  for (int j = 0; j < 576; ++j) cnt += (qw_s[j] * i) > 32767 ? 1 : 0;
  Kt_g[o * 128 + t] = (char)(cnt - 128);
}

// ---------------------------------------------------------------------------
// Kernel 2: prefetched quantize -> histogram (LDS atomics) -> i8 MFMA
// (K = 3 stacked rows x 128 bins) -> horizontal 3-sum + emit.
// ONE lgkm-only barrier per iteration. Rings: H depth 5, Sx depth 8, AK x2.
//   iter r: stage row r (r<=9) | barrier | MFMA(H[r-2..r])->AK[r&1] (2<=r<=9),
//           zero H[(r+2)%5]/Sx[(r+2)&7] (3<=r<=7, waves 6-7),
//           emit out-row r-3 from AK[(r-1)&1] (r>=3).
// grid = 512 blocks 1D, XCD-remapped (b = bid&7). 78.3 KB LDS -> 2 blk/CU.
// ---------------------------------------------------------------------------
__global__ __launch_bounds__(NTHR, 4)
void pcilt_main(const float* __restrict__ x, const float* __restrict__ bias,
                const int* __restrict__ W_tab, const char* __restrict__ Kt_g,
                float* __restrict__ out) {
  __shared__ unsigned char Hm[5][48 * HSTR];       // 34560 B: u8 bins
  __shared__ unsigned char Kt[16384];              // K'[o][v] i8
  __shared__ unsigned short AK[2][48 * AKSTR];     // 26112 B: HK' (i16) x2
  __shared__ int SxSH[8][40];                      // packed (pc<<20)|ps

  const int t   = (int)threadIdx.x;
  const int bid = (int)blockIdx.x;
  const int b  = bid & 7;                          // XCD owns one batch
  const int k  = bid >> 3;
  const int h0 = (k >> 2) * TH;
  const int w0 = (k & 3) * TW;

  for (int i = t; i < 4096; i += NTHR)
    ((unsigned int*)Kt)[i] = ((const unsigned int*)Kt_g)[i];
  {
    const uint4 z4 = make_uint4(0, 0, 0, 0);
    for (int i = t; i < 5 * 48 * HSTR / 16; i += NTHR) ((uint4*)Hm)[i] = z4;
    if (t < 320) ((int*)SxSH)[t] = 0;
  }

  const int l    = t & 15;
  const int slot = t >> 4;
  const int w    = t >> 6;
  const int kq   = (t >> 4) & 3;
  const int we   = t & 31;
  const int og   = t >> 5;

  float wf[8], bi[8];
#pragma unroll
  for (int m = 0; m < 8; ++m) {
    wf[m] = (float)W_tab[og * 8 + m];
    bi[m] = bias[og * 8 + m];
  }

  wg_barrier();

  // hoist B-fragments (Kt never overwritten)
  v4i bfr[4][2];
  const int Mt = w >> 1, Nh = w & 1;
  if (w < 6) {
#pragma unroll
    for (int nt = 0; nt < 4; ++nt)
#pragma unroll
      for (int k64 = 0; k64 < 2; ++k64)
        bfr[nt][k64] = *(const v4i*)(Kt + (Nh * 64 + nt * 16 + l) * 128 +
                                     k64 * 64 + kq * 16);
  }

  float pf0[4], pf1[4];
  const float* xb = x + ((size_t)b * CIN + l * 4) * (HW * HW);
  const size_t cs = (size_t)HW * HW;

#define ISSUE(rn)                                                              \
  {                                                                            \
    const int iy  = h0 + (rn)-1;                                               \
    const int iyc = iy < 0 ? 0 : (iy > 127 ? 127 : iy);                        \
    const bool rok = (iy >= 0) && (iy < HW);                                   \
    int ix = w0 + slot - 1;                                                    \
    int ixc = ix < 0 ? 0 : (ix > 127 ? 127 : ix);                              \
    bool ok = rok && (ix >= 0) && (ix < HW);                                   \
    const float* xp = xb + (size_t)iyc * HW + ixc;                             \
    float v0 = xp[0], v1 = xp[cs], v2 = xp[2 * cs], v3 = xp[3 * cs];           \
    pf0[0] = ok ? v0 : 0.f; pf0[1] = ok ? v1 : 0.f;                            \
    pf0[2] = ok ? v2 : 0.f; pf0[3] = ok ? v3 : 0.f;                            \
    if (slot < 2) {                                                            \
      ix = w0 + 32 + slot - 1;                                                 \
      ixc = ix > 127 ? 127 : ix;                                               \
      ok = rok && (ix < HW);                                                   \
      const float* xq = xb + (size_t)iyc * HW + ixc;                           \
      float u0 = xq[0], u1 = xq[cs], u2 = xq[2 * cs], u3 = xq[3 * cs];         \
      pf1[0] = ok ? u0 : 0.f; pf1[1] = ok ? u1 : 0.f;                          \
      pf1[2] = ok ? u2 : 0.f; pf1[3] = ok ? u3 : 0.f;                          \
    }                                                                          \
  }

#define STAGEPX(pf, px)                                                        \
  {                                                                            \
    int q, iv0, iv1, iv2, iv3;                                                 \
    q = (int)rintf((pf)[0] * 255.f); iv0 = q < 0 ? 0 : (q > 255 ? 255 : q);    \
    q = (int)rintf((pf)[1] * 255.f); iv1 = q < 0 ? 0 : (q > 255 ? 255 : q);    \
    q = (int)rintf((pf)[2] * 255.f); iv2 = q < 0 ? 0 : (q > 255 ? 255 : q);    \
    q = (int)rintf((pf)[3] * 255.f); iv3 = q < 0 ? 0 : (q > 255 ? 255 : q);    \
    int ps = iv0 + iv1 + iv2 + iv3;                                            \
    int pc = (iv0 > 128) + (iv1 > 128) + (iv2 > 128) + (iv3 > 128);            \
    atomicAdd(&Sp[px], (pc << 20) + ps);                                       \
    unsigned char* hp = Hc + (px)*HSTR;                                        \
    if (iv0 > 128) { int v = iv0 - 128; atomicAdd((unsigned int*)(hp + ((v >> 2) << 2)), 1u << ((v & 3) * 8)); } \
    if (iv1 > 128) { int v = iv1 - 128; atomicAdd((unsigned int*)(hp + ((v >> 2) << 2)), 1u << ((v & 3) * 8)); } \
    if (iv2 > 128) { int v = iv2 - 128; atomicAdd((unsigned int*)(hp + ((v >> 2) << 2)), 1u << ((v & 3) * 8)); } \
    if (iv3 > 128) { int v = iv3 - 128; atomicAdd((unsigned int*)(hp + ((v >> 2) << 2)), 1u << ((v & 3) * 8)); } \
  }

  ISSUE(0);

  for (int r = 0; r < NITER; ++r) {
    // ---------------- stage row r from prefetched regs; issue row r+1 ------
    if (r <= TH + 1) {
      unsigned char* Hc = (unsigned char*)Hm[r % 5];
      int* Sp = SxSH[r & 7];
      STAGEPX(pf0, slot);
      if (slot < 2) STAGEPX(pf1, 32 + slot);
      if (r + 1 <= TH + 1) ISSUE(r + 1);
    }
    wg_barrier();

    // ---------------- phase 2 ---------------------------------------------
    if (r >= 2 && r <= TH + 1 && w < 6) {        // MFMA -> AK[r&1]
      v4i acc[4];
#pragma unroll
      for (int nt = 0; nt < 4; ++nt) acc[nt] = (v4i){0, 0, 0, 0};
      const int prow = Mt * 16 + (t & 15);
#pragma unroll
      for (int st = 0; st < 3; ++st) {
        const unsigned char* Hs = (const unsigned char*)Hm[(r - 2 + st) % 5] +
                                  prow * HSTR + kq * 16;
#pragma unroll
        for (int k64 = 0; k64 < 2; ++k64) {
          const v4i a = *(const v4i*)(Hs + k64 * 64);
#pragma unroll
          for (int nt = 0; nt < 4; ++nt)
            acc[nt] = __builtin_amdgcn_mfma_i32_16x16x64_i8(a, bfr[nt][k64], acc[nt], 0, 0, 0);
        }
      }
      unsigned short* AKw = AK[r & 1];
      const int pbase = Mt * 16 + kq * 4;
#pragma unroll
      for (int nt = 0; nt < 4; ++nt) {
        const int o = Nh * 64 + nt * 16 + (t & 15);
#pragma unroll
        for (int rg = 0; rg < 4; ++rg)
          AKw[(pbase + rg) * AKSTR + o] = (unsigned short)acc[nt][rg];
      }
    }
    if (w >= 6 && r >= 3 && r <= TH - 1) {       // zero ring slots r+2
      const uint4 z4 = make_uint4(0, 0, 0, 0);
      uint4* Hn = (uint4*)Hm[(r + 2) % 5];
      for (int i = t - 384; i < 34 * HSTR / 16; i += 128) Hn[i] = z4;
      if (t - 384 < 40) SxSH[(r + 2) & 7][t - 384] = 0;
    }

    // ---------------- emit out-row h0 + r - 3 from AK[(r-1)&1] -------------
    if (r >= 3) {
      const int h = h0 + r - 3;
      const unsigned short* AKr = AK[(r - 1) & 1];
      int v9 = 0;
#pragma unroll
      for (int q = 0; q < 3; ++q) {
        const int sl = (r - 3 + q) & 7;
        v9 += SxSH[sl][we] + SxSH[sl][we + 1] + SxSH[sl][we + 2];
      }
      const int sx9 = v9 & 0xFFFFF;
      const int sh9 = v9 >> 20;
      int k0 = 0, k1 = 0, k2 = 0, k3 = 0, k4 = 0, k5 = 0, k6 = 0, k7 = 0;
#pragma unroll
      for (int dx = 0; dx < 3; ++dx) {
        const uint4 p = *(const uint4*)&AKr[(we + dx) * AKSTR + og * 8];
        k0 += (int)(short)(p.x & 0xffffu); k1 += (int)(short)(p.x >> 16);
        k2 += (int)(short)(p.y & 0xffffu); k3 += (int)(short)(p.y >> 16);
        k4 += (int)(short)(p.z & 0xffffu); k5 += (int)(short)(p.z >> 16);
        k6 += (int)(short)(p.w & 0xffffu); k7 += (int)(short)(p.w >> 16);
      }
      const int kc = 128 * sh9;
      const float sxf = (float)sx9;
      float* op = out + (((size_t)b * COUT + og * 8) * HW + h) * HW + (w0 + we);
      const size_t os = (size_t)HW * HW;
      op[0 * os] = sxf * wf[0] - 65536.f * (float)(k0 + kc) + bi[0];
      op[1 * os] = sxf * wf[1] - 65536.f * (float)(k1 + kc) + bi[1];
      op[2 * os] = sxf * wf[2] - 65536.f * (float)(k2 + kc) + bi[2];
      op[3 * os] = sxf * wf[3] - 65536.f * (float)(k3 + kc) + bi[3];
      op[4 * os] = sxf * wf[4] - 65536.f * (float)(k4 + kc) + bi[4];
      op[5 * os] = sxf * wf[5] - 65536.f * (float)(k5 + kc) + bi[5];
      op[6 * os] = sxf * wf[6] - 65536.f * (float)(k6 + kc) + bi[6];
      op[7 * os] = sxf * wf[7] - 65536.f * (float)(k7 + kc) + bi[7];
    }
  }
}

// ---------------------------------------------------------------------------
extern "C" void kernel_launch(void* const* d_in, const int* in_sizes, int n_in,
                              void* d_out, int out_size, void* d_ws, size_t ws_size,
                              hipStream_t stream) {
  const float* x      = (const float*)d_in[0];
  const float* weight = (const float*)d_in[1];
  const float* bias   = (const float*)d_in[2];
  float* out = (float*)d_out;

  int*  W_tab = (int*)d_ws;
  char* Kt_g  = (char*)d_ws + 512;

  build_tables<<<128, 128, 0, stream>>>(weight, W_tab, Kt_g);

  pcilt_main<<<512, NTHR, 0, stream>>>(x, bias, W_tab, Kt_g, out);
}